// Round 2
// baseline (8467.994 us; speedup 1.0000x reference)
//
#include <hip/hip_runtime.h>
#include <stdint.h>

// ---------------- problem constants ----------------
#define S_LEN 512
#define B_SZ  64
#define E_DIM 512
#define HD    1024
#define NGATE 3072   // 3*HD (r,z,c)
#define O_DIM 10

typedef __attribute__((ext_vector_type(4))) float f32x4;
typedef __attribute__((ext_vector_type(8))) short bf16x8;   // 8 bf16 in 4 VGPRs

__device__ __forceinline__ float bf2f(unsigned short u) {
  union { unsigned int i; float f; } c; c.i = ((unsigned int)u) << 16; return c.f;
}
__device__ __forceinline__ unsigned short f2bf(float f) {   // RNE
  union { float f; unsigned int i; } c; c.f = f;
  unsigned int u = c.i;
  return (unsigned short)((u + 0x7fffu + ((u >> 16) & 1u)) >> 16);
}
__device__ __forceinline__ float sigmoid_fast(float x) { return 1.0f / (1.0f + __expf(-x)); }
__device__ __forceinline__ float tanh_fast(float x) {
  float a = fabsf(x);
  float e = __expf(2.0f * a);
  return copysignf(1.0f - 2.0f / (e + 1.0f), x);
}
__device__ __forceinline__ f32x4 mfma16(bf16x8 a, bf16x8 b, f32x4 c) {
  return __builtin_amdgcn_mfma_f32_16x16x32_bf16(a, b, c, 0, 0, 0);
}
// ---- device-coherent primitives (LLC message passing) ----
__device__ __forceinline__ unsigned long long ld_u64_agent(const unsigned long long* p) {
  return __hip_atomic_load(p, __ATOMIC_RELAXED, __HIP_MEMORY_SCOPE_AGENT);
}
__device__ __forceinline__ void st_u64_agent(unsigned long long* p, unsigned long long v) {
  __hip_atomic_store(p, v, __ATOMIC_RELAXED, __HIP_MEMORY_SCOPE_AGENT);
}

// ---------------- ws layout (bytes) ----------------
// R5: SELF-TAGGED exchange. Every exchanged u32 = (bf16<<16)|seq16.
// No flags, no xchg, no vmcnt drains, no release ops, no global barrier:
// producers fire relaxed agent stores; consumers poll the data words until
// tag==round.  Serial chain per phase: ~1.5 LLC RT (was ~3-4).
// Safety: exact-match tags + transitive dataflow (a block writes round N
// only after observing full round N-1, which required all blocks' round-N-2
// reads to have completed) => no overwrite-before-read, no deadlock, no ABA.
// memset-zero == valid H0 with the step-0 expected tag (0).
#define OFF_HT    0          // u32 Ht[2][4][16][1024] tagged H   = 512 KB
#define OFF_RT    524288     // u32 Rt[4][16][1024]   tagged rh  = 256 KB
#define OFF_HF    786432     // f32 Hf[64][1024] (last step)     = 256 KB
#define OFF_ZSCR  786432     // memset end (Ht + Rt; Hf needs no zeroing)
#define OFF_WR    1704960
#define OFF_WZ    3802112
#define OFF_WC    5899264
#define OFF_WX    7996416
#define OFF_XP    11142144

// ============================================================================
// convert: fp32 weights -> bf16, pre-swizzled into MFMA B-fragment order.
// ============================================================================
__global__ void convert_kernel(const float* __restrict__ Whr, const float* __restrict__ Whz,
                               const float* __restrict__ Whc,
                               const float* __restrict__ Wxr, const float* __restrict__ Wxz,
                               const float* __restrict__ Wxc,
                               unsigned short* __restrict__ Wr_swz, unsigned short* __restrict__ Wz_swz,
                               unsigned short* __restrict__ Wc_swz, unsigned short* __restrict__ Wx_swz) {
  long idx = (long)blockIdx.x * blockDim.x + threadIdx.x;
  const long NH = (long)HD * HD;
  if (idx < 3 * NH) {
    int m = (int)(idx >> 20);
    int t = (int)(idx & (NH - 1));
    int k = t >> 10, j = t & 1023;
    const float* src = (m == 0) ? Whr : (m == 1) ? Whz : Whc;
    unsigned short* dst = (m == 0) ? Wr_swz : (m == 1) ? Wz_swz : Wc_swz;
    int jt = j >> 4, n = j & 15, kt = k >> 5, q = (k >> 3) & 3, i = k & 7;
    dst[((long)(jt * 32 + kt) * 64 + (q * 16 + n)) * 8 + i] = f2bf(src[(long)k * HD + j]);
  } else {
    long t = idx - 3 * NH;
    if (t < (long)E_DIM * NGATE) {
      int e  = (int)(t / NGATE);
      int jg = (int)(t - (long)e * NGATE);
      int jt = jg >> 4, n = jg & 15, kt = e >> 5, q = (e >> 3) & 3, i = e & 7;
      int gate = jg >> 10, jj = jg & 1023;
      const float* src = (gate == 0) ? Wxr : (gate == 1) ? Wxz : Wxc;
      Wx_swz[((long)(jt * 16 + kt) * 64 + (q * 16 + n)) * 8 + i] = f2bf(src[(long)e * HD + jj]);
    }
  }
}

// ============================================================================
// embed + X-projection -> Xp[s][g][jglob][16b] (bf16, bias folded in).
// ============================================================================
__launch_bounds__(256, 2)
__global__ void embed_kernel(const int* __restrict__ tokens,
                             const float* __restrict__ Emb,
                             const unsigned short* __restrict__ Wx_swz,
                             const float* __restrict__ b_r, const float* __restrict__ b_z,
                             const float* __restrict__ b_c,
                             unsigned short* __restrict__ Xp) {
  __shared__ unsigned short xl[B_SZ * E_DIM];   // 64 KB
  const int s = blockIdx.y;
  const int slab = blockIdx.x;                  // 0..47
  const int tid = threadIdx.x;
  for (int it = 0; it < 32; ++it) {
    int task = tid + 256 * it;
    int row = task >> 7;
    int f = task & 127;
    int tok = tokens[row * S_LEN + s];
    float4 v = *(const float4*)(Emb + (long)tok * E_DIM + f * 4);
    int sw = (f >> 1) ^ (row & 7);
    unsigned short* p = xl + row * E_DIM + sw * 8 + (f & 1) * 4;
    p[0] = f2bf(v.x); p[1] = f2bf(v.y); p[2] = f2bf(v.z); p[3] = f2bf(v.w);
  }
  __syncthreads();
  const int lane = tid & 63, wave = tid >> 6;
  const int n = lane & 15, q = lane >> 4;
  const int jt_glob = slab * 4 + wave;
  f32x4 acc[4];
  #pragma unroll
  for (int bt = 0; bt < 4; ++bt) { acc[bt][0]=0.f; acc[bt][1]=0.f; acc[bt][2]=0.f; acc[bt][3]=0.f; }
  for (int kt = 0; kt < 16; ++kt) {
    bf16x8 bfrag = *(const bf16x8*)(Wx_swz + ((long)(jt_glob * 16 + kt) * 64 + lane) * 8);
    #pragma unroll
    for (int bt = 0; bt < 4; ++bt) {
      int row = bt * 16 + n;
      int chunk = (kt * 4 + q) ^ (row & 7);
      bf16x8 afrag = *(const bf16x8*)(xl + row * E_DIM + chunk * 8);
      acc[bt] = mfma16(afrag, bfrag, acc[bt]);
    }
  }
  const int jglob = jt_glob * 16 + n;
  const int gate = jglob >> 10, jj = jglob & 1023;
  const float bias = (gate == 0 ? b_r : gate == 1 ? b_z : b_c)[jj];
  #pragma unroll
  for (int bt = 0; bt < 4; ++bt) {              // bt == batch group
    unsigned int lo = (unsigned)f2bf(acc[bt][0] + bias) | ((unsigned)f2bf(acc[bt][1] + bias) << 16);
    unsigned int hi = (unsigned)f2bf(acc[bt][2] + bias) | ((unsigned)f2bf(acc[bt][3] + bias) << 16);
    uint2 pk; pk.x = lo; pk.y = hi;             // rows 4q..4q+3 within group
    *(uint2*)(Xp + (((long)s * 4 + bt) * NGATE + jglob) * 16 + q * 4) = pk;
  }
}

// ============================================================================
// persistent GRU, self-tagged LLC exchange (R5):
//   - 128 blocks: 4 groups x 32 blocks, weights slice-resident
//   - per phase: poll tagged A-words until tag==round -> MFMA -> LDS reduce ->
//     gate math -> fire-and-forget tagged stores. ONE __syncthreads per phase
//     (LDS hazard only). No flags / no vmcnt drains / no release ops.
// ============================================================================
__launch_bounds__(256, 1)
__global__ void gru_kernel(const unsigned short* __restrict__ Xp,
                           const unsigned short* __restrict__ Wr_swz,
                           const unsigned short* __restrict__ Wz_swz,
                           const unsigned short* __restrict__ Wc_swz,
                           unsigned int* __restrict__ Ht,      // [2][4][16][1024] tagged
                           float* __restrict__ Hf,             // [64][1024] f32 (last step)
                           unsigned int* __restrict__ Rt) {    // [4][16][1024] tagged
  __shared__ float red[4][4][256];              // 16 KB [src wave][tile][...]
  __shared__ float zbuf[2][256];                // 2 KB
  __shared__ unsigned int ldsT[2][256];         // 2 KB transpose staging (tagged u32)
  __shared__ float hmaster[16 * 32];            // 2 KB fp32 H master [row][col]

  const int tid = threadIdx.x;
  const int lane = tid & 63, w = tid >> 6;
  const int n = lane & 15, q = lane >> 4;
  const int blk = blockIdx.x;                   // 0..127
  const int g  = blk & 3;                       // batch group (rows 16g..16g+15)
  const int bh = blk >> 2;                      // j-slice [32bh, 32bh+32), bh 0..31
  const int row_t = lane >> 2, word_t = lane & 3;

  // ---- weights -> registers: per-wave K-quarter (kt = w*8..w*8+7), 2 j-tiles ----
  bf16x8 wr_reg[2][8], wz_reg[2][8], wc_reg[2][8];
  #pragma unroll
  for (int jt = 0; jt < 2; ++jt)
    #pragma unroll
    for (int t = 0; t < 8; ++t) {
      long o = ((long)((2 * bh + jt) * 32 + w * 8 + t)) * 512 + lane * 8;
      wr_reg[jt][t] = *(const bf16x8*)(Wr_swz + o);
      wz_reg[jt][t] = *(const bf16x8*)(Wz_swz + o);
      wc_reg[jt][t] = *(const bf16x8*)(Wc_swz + o);
    }
  for (int i = tid; i < 512; i += 256) hmaster[i] = 0.f;   // H0 = 0
  __syncthreads();

  // Xp pointers: wave w's phase-1 tile = (gate w>>1, jt w&1); waves 0,1 also c-tile w
  const int gate_w = w >> 1, jt_w = w & 1;
  const long xp_stride = (long)4 * NGATE * 16;   // shorts per step
  const unsigned short* xp1_p = Xp + (((long)g * NGATE) + gate_w * HD + bh * 32 + jt_w * 16 + n) * 16 + q * 4;
  const unsigned short* xpc_p = Xp + (((long)g * NGATE) + 2 * HD + bh * 32 + w * 16 + n) * 16 + q * 4;

  uint2 xp1 = *(const uint2*)xp1_p;              // step 0
  uint2 xpc; xpc.x = 0; xpc.y = 0;
  if (w < 2) xpc = *(const uint2*)(xpc_p);

  const unsigned long long TAGMASK = 0x0000FFFF0000FFFFull;
  int cur = 0;

  for (int s = 0; s < S_LEN; ++s) {
    const long s_next = (s < S_LEN - 1) ? (long)(s + 1) : (long)s;
    const unsigned int expH = 2u * (unsigned int)s;   // tag on Ht[cur] (0 at s=0: memset)
    const unsigned int tagR = expH + 1u;              // tag we write on rh this step
    const unsigned int tagH = expH + 2u;              // tag we write on Ht[cur^1]

    // ============ phase 1: r,z (4 tiles), K-quarter per wave ============
    {
      // prefetch next step's Xp (overlaps poll latency)
      uint2 xp1n = *(const uint2*)(xp1_p + s_next * xp_stride);
      uint2 xpcn; xpcn.x = 0; xpcn.y = 0;
      if (w < 2) xpcn = *(const uint2*)(xpc_p + s_next * xp_stride);

      // ---- poll tagged H words: lane (n,q), kt = w*8..w*8+7, cols kt*32+q*8..+8
      const unsigned long long* Ab =
          (const unsigned long long*)Ht + ((long)(cur * 4 + g) * 16 + n) * 512 + q * 4;
      unsigned long long a[8][4];
      {
        const unsigned long long pat =
            (unsigned long long)expH | ((unsigned long long)expH << 32);
        for (;;) {
          int ok = 1;
          #pragma unroll
          for (int t = 0; t < 8; ++t) {
            const unsigned long long* p = Ab + (long)(w * 8 + t) * 16;
            #pragma unroll
            for (int u = 0; u < 4; ++u) a[t][u] = ld_u64_agent(p + u);
          }
          #pragma unroll
          for (int t = 0; t < 8; ++t)
            #pragma unroll
            for (int u = 0; u < 4; ++u) ok &= ((a[t][u] & TAGMASK) == pat);
          if (__all(ok)) break;
          __builtin_amdgcn_s_sleep(1);
        }
      }

      f32x4 aR0, aR1, aZ0, aZ1;
      aR0[0]=0.f;aR0[1]=0.f;aR0[2]=0.f;aR0[3]=0.f; aR1=aR0; aZ0=aR0; aZ1=aR0;
      #pragma unroll
      for (int t = 0; t < 8; ++t) {
        union { unsigned int u[4]; bf16x8 v; } af;
        #pragma unroll
        for (int j = 0; j < 4; ++j) {
          unsigned long long x = a[t][j];
          af.u[j] = ((unsigned int)x >> 16) | ((unsigned int)(x >> 32) & 0xFFFF0000u);
        }
        aR0 = mfma16(af.v, wr_reg[0][t], aR0);
        aR1 = mfma16(af.v, wr_reg[1][t], aR1);
        aZ0 = mfma16(af.v, wz_reg[0][t], aZ0);
        aZ1 = mfma16(af.v, wz_reg[1][t], aZ1);
      }
      *(f32x4*)&red[w][0][lane * 4] = aR0;
      *(f32x4*)&red[w][1][lane * 4] = aR1;
      *(f32x4*)&red[w][2][lane * 4] = aZ0;
      *(f32x4*)&red[w][3][lane * 4] = aZ1;
      __syncthreads();
      // wave t reduces tile t; tile == wave's own xp1 tile by construction
      f32x4 acc = *(const f32x4*)&red[0][w][lane * 4];
      #pragma unroll
      for (int k = 1; k < 4; ++k) { f32x4 p = *(const f32x4*)&red[k][w][lane * 4]; acc += p; }
      if (w < 2) {            // r tiles: rh = sigmoid(.)*H -> transpose -> tagged store
        #pragma unroll
        for (int r_ = 0; r_ < 4; ++r_) {
          float xpv = bf2f((unsigned short)(((r_ < 2) ? xp1.x : xp1.y) >> ((r_ & 1) * 16)));
          float rv = sigmoid_fast(acc[r_] + xpv);
          ldsT[w][(q * 4 + r_) * 16 + n] =
              ((unsigned int)f2bf(rv * hmaster[(q * 4 + r_) * 32 + w * 16 + n]) << 16) | tagR;
        }
        asm volatile("s_waitcnt lgkmcnt(0)" ::: "memory");
        const unsigned long long* src =
            (const unsigned long long*)&ldsT[w][row_t * 16 + word_t * 4];
        unsigned long long* dst = (unsigned long long*)Rt +
            ((long)(g * 16 + row_t) * 512 + bh * 16 + w * 8 + word_t * 2);
        st_u64_agent(dst, src[0]);
        st_u64_agent(dst + 1, src[1]);
      } else {                // z tiles -> zbuf
        #pragma unroll
        for (int r_ = 0; r_ < 4; ++r_) {
          float xpv = bf2f((unsigned short)(((r_ < 2) ? xp1.x : xp1.y) >> ((r_ & 1) * 16)));
          zbuf[w - 2][(q * 4 + r_) * 16 + n] = sigmoid_fast(acc[r_] + xpv);
        }
      }
      xp1 = xp1n;
      __syncthreads();        // LDS hazard only (red/zbuf/ldsT reuse)

      // ============ phase 2: c (2 tiles), K-quarter per wave ============
      const unsigned long long* Rb =
          (const unsigned long long*)Rt + ((long)(g * 16 + n) * 512 + q * 4);
      unsigned long long c[8][4];
      {
        const unsigned long long pat =
            (unsigned long long)tagR | ((unsigned long long)tagR << 32);
        for (;;) {
          int ok = 1;
          #pragma unroll
          for (int t = 0; t < 8; ++t) {
            const unsigned long long* p = Rb + (long)(w * 8 + t) * 16;
            #pragma unroll
            for (int u = 0; u < 4; ++u) c[t][u] = ld_u64_agent(p + u);
          }
          #pragma unroll
          for (int t = 0; t < 8; ++t)
            #pragma unroll
            for (int u = 0; u < 4; ++u) ok &= ((c[t][u] & TAGMASK) == pat);
          if (__all(ok)) break;
          __builtin_amdgcn_s_sleep(1);
        }
      }
      f32x4 cA, cB;
      cA[0]=0.f;cA[1]=0.f;cA[2]=0.f;cA[3]=0.f; cB = cA;
      #pragma unroll
      for (int t = 0; t < 8; ++t) {
        union { unsigned int u[4]; bf16x8 v; } af;
        #pragma unroll
        for (int j = 0; j < 4; ++j) {
          unsigned long long x = c[t][j];
          af.u[j] = ((unsigned int)x >> 16) | ((unsigned int)(x >> 32) & 0xFFFF0000u);
        }
        cA = mfma16(af.v, wc_reg[0][t], cA);
        cB = mfma16(af.v, wc_reg[1][t], cB);
      }
      *(f32x4*)&red[w][0][lane * 4] = cA;
      *(f32x4*)&red[w][1][lane * 4] = cB;
      __syncthreads();
      if (w < 2) {            // wave w reduces c-tile w, updates H, tagged store
        f32x4 acc2 = *(const f32x4*)&red[0][w][lane * 4];
        #pragma unroll
        for (int k = 1; k < 4; ++k) { f32x4 p = *(const f32x4*)&red[k][w][lane * 4]; acc2 += p; }
        #pragma unroll
        for (int r_ = 0; r_ < 4; ++r_) {
          float xpv = bf2f((unsigned short)(((r_ < 2) ? xpc.x : xpc.y) >> ((r_ & 1) * 16)));
          float cv = tanh_fast(acc2[r_] + xpv);
          float z  = zbuf[w][(q * 4 + r_) * 16 + n];
          float h0 = hmaster[(q * 4 + r_) * 32 + w * 16 + n];
          float hn = z * h0 + (1.0f - z) * cv;
          hmaster[(q * 4 + r_) * 32 + w * 16 + n] = hn;
          ldsT[w][(q * 4 + r_) * 16 + n] = ((unsigned int)f2bf(hn) << 16) | tagH;
          if (s == S_LEN - 1)
            Hf[(long)(g * 16 + q * 4 + r_) * HD + bh * 32 + w * 16 + n] = hn;
        }
        asm volatile("s_waitcnt lgkmcnt(0)" ::: "memory");
        const unsigned long long* src =
            (const unsigned long long*)&ldsT[w][row_t * 16 + word_t * 4];
        unsigned long long* dst = (unsigned long long*)Ht +
            ((long)(((cur ^ 1) * 4 + g) * 16 + row_t) * 512 + bh * 16 + w * 8 + word_t * 2);
        st_u64_agent(dst, src[0]);
        st_u64_agent(dst + 1, src[1]);
        xpc = xpcn;           // advance c-tile prefetch
      }
      __syncthreads();        // LDS hazard only (red/zbuf/ldsT reuse next step)
      cur ^= 1;
    }
  }
}

// ============================================================================
// logits + softmax: one wave per batch row
// ============================================================================
__global__ void logits_kernel(const float* __restrict__ Hf, const float* __restrict__ Whq,
                              const float* __restrict__ bq, float* __restrict__ out) {
  const int b = blockIdx.x;
  const int lane = threadIdx.x;   // 64
  float acc[O_DIM];
  #pragma unroll
  for (int o = 0; o < O_DIM; ++o) acc[o] = 0.f;
  for (int k = lane; k < HD; k += 64) {
    float h = Hf[(long)b * HD + k];
    #pragma unroll
    for (int o = 0; o < O_DIM; ++o) acc[o] += h * Whq[(long)k * O_DIM + o];
  }
  #pragma unroll
  for (int o = 0; o < O_DIM; ++o) {
    #pragma unroll
    for (int off = 32; off > 0; off >>= 1) acc[o] += __shfl_down(acc[o], off, 64);
  }
  if (lane == 0) {
    float lg[O_DIM], m = -1e30f, sum = 0.f;
    #pragma unroll
    for (int o = 0; o < O_DIM; ++o) { lg[o] = acc[o] + bq[o]; m = fmaxf(m, lg[o]); }
    #pragma unroll
    for (int o = 0; o < O_DIM; ++o) { lg[o] = __expf(lg[o] - m); sum += lg[o]; }
    float inv = 1.0f / sum;
    #pragma unroll
    for (int o = 0; o < O_DIM; ++o) out[(long)b * O_DIM + o] = lg[o] * inv;
  }
}

// ============================================================================
extern "C" void kernel_launch(void* const* d_in, const int* in_sizes, int n_in,
                              void* d_out, int out_size, void* d_ws, size_t ws_size,
                              hipStream_t stream) {
  const int*   tokens = (const int*)d_in[0];
  const float* Emb = (const float*)d_in[1];
  const float* Wxr = (const float*)d_in[2];
  const float* Whr = (const float*)d_in[3];
  const float* br  = (const float*)d_in[4];
  const float* Wxz = (const float*)d_in[5];
  const float* Whz = (const float*)d_in[6];
  const float* bz  = (const float*)d_in[7];
  const float* Wxc = (const float*)d_in[8];
  const float* Whc = (const float*)d_in[9];
  const float* bc  = (const float*)d_in[10];
  const float* Whq = (const float*)d_in[11];
  const float* bq  = (const float*)d_in[12];

  char* ws = (char*)d_ws;
  unsigned int*   Ht     = (unsigned int*)(ws + OFF_HT);
  unsigned int*   Rt     = (unsigned int*)(ws + OFF_RT);
  float*          Hf     = (float*)(ws + OFF_HF);
  unsigned short* Wr_swz = (unsigned short*)(ws + OFF_WR);
  unsigned short* Wz_swz = (unsigned short*)(ws + OFF_WZ);
  unsigned short* Wc_swz = (unsigned short*)(ws + OFF_WC);
  unsigned short* Wx_swz = (unsigned short*)(ws + OFF_WX);
  unsigned short* Xp     = (unsigned short*)(ws + OFF_XP);

  // zero tagged H buffers (tag 0 == valid H0) and tagged rh (tag 0 = stale)
  hipMemsetAsync(ws, 0, OFF_ZSCR, stream);

  convert_kernel<<<18432, 256, 0, stream>>>(Whr, Whz, Whc, Wxr, Wxz, Wxc,
                                            Wr_swz, Wz_swz, Wc_swz, Wx_swz);
  embed_kernel<<<dim3(48, S_LEN), 256, 0, stream>>>(tokens, Emb, Wx_swz, br, bz, bc, Xp);
  gru_kernel<<<128, 256, 0, stream>>>(Xp, Wr_swz, Wz_swz, Wc_swz, Ht, Hf, Rt);
  logits_kernel<<<B_SZ, 64, 0, stream>>>(Hf, Whq, bq, (float*)d_out);
}

// Round 3
// 4224.091 us; speedup vs baseline: 2.0047x; 2.0047x over previous
//
#include <hip/hip_runtime.h>
#include <stdint.h>

// ---------------- problem constants ----------------
#define S_LEN 512
#define B_SZ  64
#define E_DIM 512
#define HD    1024
#define NGATE 3072   // 3*HD (r,z,c)
#define O_DIM 10

typedef __attribute__((ext_vector_type(4))) float f32x4;
typedef __attribute__((ext_vector_type(8))) short bf16x8;   // 8 bf16 in 4 VGPRs

__device__ __forceinline__ float bf2f(unsigned short u) {
  union { unsigned int i; float f; } c; c.i = ((unsigned int)u) << 16; return c.f;
}
__device__ __forceinline__ unsigned short f2bf(float f) {   // RNE
  union { float f; unsigned int i; } c; c.f = f;
  unsigned int u = c.i;
  return (unsigned short)((u + 0x7fffu + ((u >> 16) & 1u)) >> 16);
}
__device__ __forceinline__ float sigmoid_fast(float x) { return 1.0f / (1.0f + __expf(-x)); }
__device__ __forceinline__ float tanh_fast(float x) {
  float a = fabsf(x);
  float e = __expf(2.0f * a);
  return copysignf(1.0f - 2.0f / (e + 1.0f), x);
}
__device__ __forceinline__ f32x4 mfma16(bf16x8 a, bf16x8 b, f32x4 c) {
  return __builtin_amdgcn_mfma_f32_16x16x32_bf16(a, b, c, 0, 0, 0);
}
// ---- device-coherent primitives (LLC message passing) ----
// R6: ALL relaxed. Plain sc1 stores (R5-proven to propagate) replace the
// xchg RMW (no return path to drain on).  The RELEASE flag store is replaced
// by {explicit per-wave vmcnt(0) drain -> __syncthreads -> RELAXED store}:
// same ordering, no compiler-emitted cache-maintenance (wbl2-class ops).
__device__ __forceinline__ unsigned long long ld_u64_agent(const unsigned long long* p) {
  return __hip_atomic_load(p, __ATOMIC_RELAXED, __HIP_MEMORY_SCOPE_AGENT);
}
__device__ __forceinline__ void st_u64_agent(unsigned long long* p, unsigned long long v) {
  __hip_atomic_store(p, v, __ATOMIC_RELAXED, __HIP_MEMORY_SCOPE_AGENT);
}
__device__ __forceinline__ unsigned int ld_u32_agent(const unsigned int* p) {
  return __hip_atomic_load(p, __ATOMIC_RELAXED, __HIP_MEMORY_SCOPE_AGENT);
}
__device__ __forceinline__ void st_u32_agent(unsigned int* p, unsigned int v) {
  __hip_atomic_store(p, v, __ATOMIC_RELAXED, __HIP_MEMORY_SCOPE_AGENT);
}

// ---------------- ws layout (bytes) ----------------
// Flags stay padded to one 256B line each (R4, -4%).
#define SLOT_STRIDE 64       // u32s per flag slot = 256 B
#define OFF_HBF   0          // [2][64][1024] bf16 = 256 KB
#define OFF_HF    262144     // [64][1024] f32  = 256 KB
#define OFF_SLOTS 524288     // [4][32] u32, each padded to 256 B = 32 KB
#define OFF_ZSCR  557056     // memset end (covers Hbf, Hf, slots)
#define OFF_RH    1573888
#define OFF_WR    1704960
#define OFF_WZ    3802112
#define OFF_WC    5899264
#define OFF_WX    7996416
#define OFF_XP    11142144

// ============================================================================
// convert: fp32 weights -> bf16, pre-swizzled into MFMA B-fragment order.
// ============================================================================
__global__ void convert_kernel(const float* __restrict__ Whr, const float* __restrict__ Whz,
                               const float* __restrict__ Whc,
                               const float* __restrict__ Wxr, const float* __restrict__ Wxz,
                               const float* __restrict__ Wxc,
                               unsigned short* __restrict__ Wr_swz, unsigned short* __restrict__ Wz_swz,
                               unsigned short* __restrict__ Wc_swz, unsigned short* __restrict__ Wx_swz) {
  long idx = (long)blockIdx.x * blockDim.x + threadIdx.x;
  const long NH = (long)HD * HD;
  if (idx < 3 * NH) {
    int m = (int)(idx >> 20);
    int t = (int)(idx & (NH - 1));
    int k = t >> 10, j = t & 1023;
    const float* src = (m == 0) ? Whr : (m == 1) ? Whz : Whc;
    unsigned short* dst = (m == 0) ? Wr_swz : (m == 1) ? Wz_swz : Wc_swz;
    int jt = j >> 4, n = j & 15, kt = k >> 5, q = (k >> 3) & 3, i = k & 7;
    dst[((long)(jt * 32 + kt) * 64 + (q * 16 + n)) * 8 + i] = f2bf(src[(long)k * HD + j]);
  } else {
    long t = idx - 3 * NH;
    if (t < (long)E_DIM * NGATE) {
      int e  = (int)(t / NGATE);
      int jg = (int)(t - (long)e * NGATE);
      int jt = jg >> 4, n = jg & 15, kt = e >> 5, q = (e >> 3) & 3, i = e & 7;
      int gate = jg >> 10, jj = jg & 1023;
      const float* src = (gate == 0) ? Wxr : (gate == 1) ? Wxz : Wxc;
      Wx_swz[((long)(jt * 16 + kt) * 64 + (q * 16 + n)) * 8 + i] = f2bf(src[(long)e * HD + jj]);
    }
  }
}

// ============================================================================
// embed + X-projection -> Xp[s][g][jglob][16b] (bf16, bias folded in).
// ============================================================================
__launch_bounds__(256, 2)
__global__ void embed_kernel(const int* __restrict__ tokens,
                             const float* __restrict__ Emb,
                             const unsigned short* __restrict__ Wx_swz,
                             const float* __restrict__ b_r, const float* __restrict__ b_z,
                             const float* __restrict__ b_c,
                             unsigned short* __restrict__ Xp) {
  __shared__ unsigned short xl[B_SZ * E_DIM];   // 64 KB
  const int s = blockIdx.y;
  const int slab = blockIdx.x;                  // 0..47
  const int tid = threadIdx.x;
  for (int it = 0; it < 32; ++it) {
    int task = tid + 256 * it;
    int row = task >> 7;
    int f = task & 127;
    int tok = tokens[row * S_LEN + s];
    float4 v = *(const float4*)(Emb + (long)tok * E_DIM + f * 4);
    int sw = (f >> 1) ^ (row & 7);
    unsigned short* p = xl + row * E_DIM + sw * 8 + (f & 1) * 4;
    p[0] = f2bf(v.x); p[1] = f2bf(v.y); p[2] = f2bf(v.z); p[3] = f2bf(v.w);
  }
  __syncthreads();
  const int lane = tid & 63, wave = tid >> 6;
  const int n = lane & 15, q = lane >> 4;
  const int jt_glob = slab * 4 + wave;
  f32x4 acc[4];
  #pragma unroll
  for (int bt = 0; bt < 4; ++bt) { acc[bt][0]=0.f; acc[bt][1]=0.f; acc[bt][2]=0.f; acc[bt][3]=0.f; }
  for (int kt = 0; kt < 16; ++kt) {
    bf16x8 bfrag = *(const bf16x8*)(Wx_swz + ((long)(jt_glob * 16 + kt) * 64 + lane) * 8);
    #pragma unroll
    for (int bt = 0; bt < 4; ++bt) {
      int row = bt * 16 + n;
      int chunk = (kt * 4 + q) ^ (row & 7);
      bf16x8 afrag = *(const bf16x8*)(xl + row * E_DIM + chunk * 8);
      acc[bt] = mfma16(afrag, bfrag, acc[bt]);
    }
  }
  const int jglob = jt_glob * 16 + n;
  const int gate = jglob >> 10, jj = jglob & 1023;
  const float bias = (gate == 0 ? b_r : gate == 1 ? b_z : b_c)[jj];
  #pragma unroll
  for (int bt = 0; bt < 4; ++bt) {              // bt == batch group
    unsigned int lo = (unsigned)f2bf(acc[bt][0] + bias) | ((unsigned)f2bf(acc[bt][1] + bias) << 16);
    unsigned int hi = (unsigned)f2bf(acc[bt][2] + bias) | ((unsigned)f2bf(acc[bt][3] + bias) << 16);
    uint2 pk; pk.x = lo; pk.y = hi;             // rows 4q..4q+3 within group
    *(uint2*)(Xp + (((long)s * 4 + bt) * NGATE + jglob) * 16 + q * 4) = pk;
  }
}

// ============================================================================
// persistent GRU = R4 skeleton (proven 4.66 ms) with three de-fattening edits:
//   1. payload xchg RMW -> plain relaxed sc1 store (no return path)
//   2. RELEASE flag -> {vmcnt(0) drain, barrier, RELAXED flag} (no compiler
//      cache-maintenance on the critical path)
//   3. all 4 waves poll flags independently; trailing barrier per phase
//      deleted (each wave self-releases the instant flags land).
//      Hazard audit: red/zbuf reuse fenced by the pre-flag barrier; rh/Hbf
//      overwrite safety transitive through the flag chain (unchanged).
// ============================================================================
__launch_bounds__(256, 1)
__global__ void gru_kernel(const unsigned short* __restrict__ Xp,
                           const unsigned short* __restrict__ Wr_swz,
                           const unsigned short* __restrict__ Wz_swz,
                           const unsigned short* __restrict__ Wc_swz,
                           unsigned short* __restrict__ Hbf,    // [2][64][1024] bf16
                           float* __restrict__ Hf,              // [64][1024] f32 (last step)
                           unsigned short* __restrict__ rh,     // [64][1024] bf16
                           unsigned int* __restrict__ slots) {  // [4][32] padded x64
  __shared__ float red[4][4][256];              // 16 KB [src wave][tile][...]
  __shared__ float zbuf[2][256];                // 2 KB
  __shared__ unsigned short ldsT[2][256];       // 1 KB transpose staging
  __shared__ float hmaster[16 * 32];            // 2 KB fp32 H master [row][col]

  const int tid = threadIdx.x;
  const int lane = tid & 63, w = tid >> 6;
  const int n = lane & 15, q = lane >> 4;
  const int blk = blockIdx.x;                   // 0..127
  const int g  = blk & 3;                       // batch group (rows 16g..16g+15)
  const int bh = blk >> 2;                      // j-slice [32bh, 32bh+32), bh 0..31
  const int row_t = lane >> 2, word_t = lane & 3;

  // ---- weights -> registers: per-wave K-quarter (kt = w*8..w*8+7), 2 j-tiles ----
  bf16x8 wr_reg[2][8], wz_reg[2][8], wc_reg[2][8];
  #pragma unroll
  for (int jt = 0; jt < 2; ++jt)
    #pragma unroll
    for (int t = 0; t < 8; ++t) {
      long o = ((long)((2 * bh + jt) * 32 + w * 8 + t)) * 512 + lane * 8;
      wr_reg[jt][t] = *(const bf16x8*)(Wr_swz + o);
      wz_reg[jt][t] = *(const bf16x8*)(Wz_swz + o);
      wc_reg[jt][t] = *(const bf16x8*)(Wc_swz + o);
    }
  for (int i = tid; i < 512; i += 256) hmaster[i] = 0.f;   // H0 = 0
  __syncthreads();

  unsigned int* slot_base = slots + g * 32 * SLOT_STRIDE;
  unsigned long long* rh_u64 = (unsigned long long*)rh;

  // Xp pointers: wave w's phase-1 tile = (gate w>>1, jt w&1); waves 0,1 also c-tile w
  const int gate_w = w >> 1, jt_w = w & 1;
  const long xp_stride = (long)4 * NGATE * 16;   // shorts per step
  const unsigned short* xp1_p = Xp + (((long)g * NGATE) + gate_w * HD + bh * 32 + jt_w * 16 + n) * 16 + q * 4;
  const unsigned short* xpc_p = Xp + (((long)g * NGATE) + 2 * HD + bh * 32 + w * 16 + n) * 16 + q * 4;

  uint2 xp1 = *(const uint2*)xp1_p;              // step 0
  uint2 xpc; xpc.x = 0; xpc.y = 0;
  if (w < 2) xpc = *(const uint2*)xpc_p;

  int cur = 0;
  unsigned int seq = 1;

  for (int s = 0; s < S_LEN; ++s) {
    const long s_next = (s < S_LEN - 1) ? (long)(s + 1) : (long)s;
    // ============ phase 1: r,z (4 tiles), K-quarter per wave ============
    {
      const unsigned long long* Ab =
          (const unsigned long long*)(Hbf + (long)cur * (B_SZ * HD) + (long)(g * 16 + n) * HD + q * 8);
      unsigned long long a0[8], a1[8];
      #pragma unroll
      for (int t = 0; t < 8; ++t) {
        int kt = w * 8 + t;
        a0[t] = ld_u64_agent(Ab + kt * 8);
        a1[t] = ld_u64_agent(Ab + kt * 8 + 1);
      }
      // prefetch next step's Xp while A-loads are in flight
      uint2 xp1n = *(const uint2*)(xp1_p + s_next * xp_stride);
      uint2 xpcn; xpcn.x = 0; xpcn.y = 0;
      if (w < 2) xpcn = *(const uint2*)(xpc_p + s_next * xp_stride);

      f32x4 aR0, aR1, aZ0, aZ1;
      aR0[0]=0.f;aR0[1]=0.f;aR0[2]=0.f;aR0[3]=0.f; aR1=aR0; aZ0=aR0; aZ1=aR0;
      #pragma unroll
      for (int t = 0; t < 8; ++t) {
        union { unsigned long long u[2]; bf16x8 v; } af;
        af.u[0] = a0[t]; af.u[1] = a1[t];
        aR0 = mfma16(af.v, wr_reg[0][t], aR0);
        aR1 = mfma16(af.v, wr_reg[1][t], aR1);
        aZ0 = mfma16(af.v, wz_reg[0][t], aZ0);
        aZ1 = mfma16(af.v, wz_reg[1][t], aZ1);
      }
      *(f32x4*)&red[w][0][lane * 4] = aR0;
      *(f32x4*)&red[w][1][lane * 4] = aR1;
      *(f32x4*)&red[w][2][lane * 4] = aZ0;
      *(f32x4*)&red[w][3][lane * 4] = aZ1;
      __syncthreads();
      // wave t reduces tile t; tile == wave's own xp1 tile by construction
      f32x4 acc = *(const f32x4*)&red[0][w][lane * 4];
      #pragma unroll
      for (int k = 1; k < 4; ++k) { f32x4 p = *(const f32x4*)&red[k][w][lane * 4]; acc += p; }
      if (w < 2) {            // r tiles: rh = sigmoid(.)*H -> transpose -> store
        #pragma unroll
        for (int r_ = 0; r_ < 4; ++r_) {
          float xpv = bf2f((unsigned short)(((r_ < 2) ? xp1.x : xp1.y) >> ((r_ & 1) * 16)));
          float rv = sigmoid_fast(acc[r_] + xpv);
          ldsT[w][(q * 4 + r_) * 16 + n] = f2bf(rv * hmaster[(q * 4 + r_) * 32 + w * 16 + n]);
        }
        asm volatile("s_waitcnt lgkmcnt(0)" ::: "memory");
        unsigned long long pay = *(const unsigned long long*)(&ldsT[w][row_t * 16 + word_t * 4]);
        st_u64_agent(rh_u64 + (((long)(g * 16 + row_t) * HD + bh * 32 + w * 16 + word_t * 4) >> 2), pay);
        asm volatile("s_waitcnt vmcnt(0)" ::: "memory");   // payload at coherent point
      } else {                // z tiles -> zbuf
        #pragma unroll
        for (int r_ = 0; r_ < 4; ++r_) {
          float xpv = bf2f((unsigned short)(((r_ < 2) ? xp1.x : xp1.y) >> ((r_ & 1) * 16)));
          zbuf[w - 2][(q * 4 + r_) * 16 + n] = sigmoid_fast(acc[r_] + xpv);
        }
      }
      xp1 = xp1n;
      __syncthreads();        // all waves' payload stores drained
      if (tid == 0) st_u32_agent(slot_base + bh * SLOT_STRIDE, seq);
      asm volatile("" ::: "memory");
      if (lane < 32) {        // every wave polls; self-release, no 2nd barrier
        unsigned int v;
        do {
          v = ld_u32_agent(slot_base + lane * SLOT_STRIDE);
          if (v >= seq) break;
          __builtin_amdgcn_s_sleep(1);
        } while (true);
      }
      asm volatile("" ::: "memory");
      seq++;

      // ============ phase 2: c (2 tiles), K-quarter per wave ============
      const unsigned long long* Rb =
          (const unsigned long long*)(rh + (long)(g * 16 + n) * HD + q * 8);
      unsigned long long c0[8], c1[8];
      #pragma unroll
      for (int t = 0; t < 8; ++t) {
        int kt = w * 8 + t;
        c0[t] = ld_u64_agent(Rb + kt * 8);
        c1[t] = ld_u64_agent(Rb + kt * 8 + 1);
      }
      f32x4 cA, cB;
      cA[0]=0.f;cA[1]=0.f;cA[2]=0.f;cA[3]=0.f; cB = cA;
      #pragma unroll
      for (int t = 0; t < 8; ++t) {
        union { unsigned long long u[2]; bf16x8 v; } af;
        af.u[0] = c0[t]; af.u[1] = c1[t];
        cA = mfma16(af.v, wc_reg[0][t], cA);
        cB = mfma16(af.v, wc_reg[1][t], cB);
      }
      *(f32x4*)&red[w][0][lane * 4] = cA;
      *(f32x4*)&red[w][1][lane * 4] = cB;
      __syncthreads();
      if (w < 2) {            // wave w reduces c-tile w, updates H
        f32x4 acc2 = *(const f32x4*)&red[0][w][lane * 4];
        #pragma unroll
        for (int k = 1; k < 4; ++k) { f32x4 p = *(const f32x4*)&red[k][w][lane * 4]; acc2 += p; }
        #pragma unroll
        for (int r_ = 0; r_ < 4; ++r_) {
          float xpv = bf2f((unsigned short)(((r_ < 2) ? xpc.x : xpc.y) >> ((r_ & 1) * 16)));
          float cv = tanh_fast(acc2[r_] + xpv);
          float z  = zbuf[w][(q * 4 + r_) * 16 + n];
          float h0 = hmaster[(q * 4 + r_) * 32 + w * 16 + n];
          float hn = z * h0 + (1.0f - z) * cv;
          hmaster[(q * 4 + r_) * 32 + w * 16 + n] = hn;
          ldsT[w][(q * 4 + r_) * 16 + n] = f2bf(hn);
          if (s == S_LEN - 1)
            Hf[(long)(g * 16 + q * 4 + r_) * HD + bh * 32 + w * 16 + n] = hn;
        }
        asm volatile("s_waitcnt lgkmcnt(0)" ::: "memory");
        unsigned long long pay = *(const unsigned long long*)(&ldsT[w][row_t * 16 + word_t * 4]);
        st_u64_agent((unsigned long long*)(Hbf + (long)(cur ^ 1) * (B_SZ * HD)) +
                     (((long)(g * 16 + row_t) * HD + bh * 32 + w * 16 + word_t * 4) >> 2), pay);
        asm volatile("s_waitcnt vmcnt(0)" ::: "memory");   // payload at coherent point
        xpc = xpcn;           // advance c-tile prefetch
      }
      __syncthreads();        // all waves' payload stores drained
      if (tid == 0) st_u32_agent(slot_base + bh * SLOT_STRIDE, seq);
      asm volatile("" ::: "memory");
      if (lane < 32) {        // every wave polls; self-release, no 2nd barrier
        unsigned int v;
        do {
          v = ld_u32_agent(slot_base + lane * SLOT_STRIDE);
          if (v >= seq) break;
          __builtin_amdgcn_s_sleep(1);
        } while (true);
      }
      asm volatile("" ::: "memory");
      seq++;
      cur ^= 1;
    }
  }
}

// ============================================================================
// logits + softmax: one wave per batch row
// ============================================================================
__global__ void logits_kernel(const float* __restrict__ Hf, const float* __restrict__ Whq,
                              const float* __restrict__ bq, float* __restrict__ out) {
  const int b = blockIdx.x;
  const int lane = threadIdx.x;   // 64
  float acc[O_DIM];
  #pragma unroll
  for (int o = 0; o < O_DIM; ++o) acc[o] = 0.f;
  for (int k = lane; k < HD; k += 64) {
    float h = Hf[(long)b * HD + k];
    #pragma unroll
    for (int o = 0; o < O_DIM; ++o) acc[o] += h * Whq[(long)k * O_DIM + o];
  }
  #pragma unroll
  for (int o = 0; o < O_DIM; ++o) {
    #pragma unroll
    for (int off = 32; off > 0; off >>= 1) acc[o] += __shfl_down(acc[o], off, 64);
  }
  if (lane == 0) {
    float lg[O_DIM], m = -1e30f, sum = 0.f;
    #pragma unroll
    for (int o = 0; o < O_DIM; ++o) { lg[o] = acc[o] + bq[o]; m = fmaxf(m, lg[o]); }
    #pragma unroll
    for (int o = 0; o < O_DIM; ++o) { lg[o] = __expf(lg[o] - m); sum += lg[o]; }
    float inv = 1.0f / sum;
    #pragma unroll
    for (int o = 0; o < O_DIM; ++o) out[(long)b * O_DIM + o] = lg[o] * inv;
  }
}

// ============================================================================
extern "C" void kernel_launch(void* const* d_in, const int* in_sizes, int n_in,
                              void* d_out, int out_size, void* d_ws, size_t ws_size,
                              hipStream_t stream) {
  const int*   tokens = (const int*)d_in[0];
  const float* Emb = (const float*)d_in[1];
  const float* Wxr = (const float*)d_in[2];
  const float* Whr = (const float*)d_in[3];
  const float* br  = (const float*)d_in[4];
  const float* Wxz = (const float*)d_in[5];
  const float* Whz = (const float*)d_in[6];
  const float* bz  = (const float*)d_in[7];
  const float* Wxc = (const float*)d_in[8];
  const float* Whc = (const float*)d_in[9];
  const float* bc  = (const float*)d_in[10];
  const float* Whq = (const float*)d_in[11];
  const float* bq  = (const float*)d_in[12];

  char* ws = (char*)d_ws;
  unsigned short* Hbf    = (unsigned short*)(ws + OFF_HBF);
  float*          Hf     = (float*)(ws + OFF_HF);
  unsigned int*   slots  = (unsigned int*)(ws + OFF_SLOTS);
  unsigned short* rh     = (unsigned short*)(ws + OFF_RH);
  unsigned short* Wr_swz = (unsigned short*)(ws + OFF_WR);
  unsigned short* Wz_swz = (unsigned short*)(ws + OFF_WZ);
  unsigned short* Wc_swz = (unsigned short*)(ws + OFF_WC);
  unsigned short* Wx_swz = (unsigned short*)(ws + OFF_WX);
  unsigned short* Xp     = (unsigned short*)(ws + OFF_XP);

  // zero H0 (both bf16 H buffers), Hf, and padded barrier slots
  hipMemsetAsync(ws, 0, OFF_ZSCR, stream);

  convert_kernel<<<18432, 256, 0, stream>>>(Whr, Whz, Whc, Wxr, Wxz, Wxc,
                                            Wr_swz, Wz_swz, Wc_swz, Wx_swz);
  embed_kernel<<<dim3(48, S_LEN), 256, 0, stream>>>(tokens, Emb, Wx_swz, br, bz, bc, Xp);
  gru_kernel<<<128, 256, 0, stream>>>(Xp, Wr_swz, Wz_swz, Wc_swz,
                                      Hbf, Hf, rh, slots);
  logits_kernel<<<B_SZ, 64, 0, stream>>>(Hf, Whq, bq, (float*)d_out);
}

// Round 4
// 3552.500 us; speedup vs baseline: 2.3837x; 1.1890x over previous
//
#include <hip/hip_runtime.h>
#include <stdint.h>

// ---------------- problem constants ----------------
#define S_LEN 512
#define B_SZ  64
#define E_DIM 512
#define HD    1024
#define NGATE 3072   // 3*HD (r,z,c)
#define O_DIM 10

typedef __attribute__((ext_vector_type(4))) float f32x4;
typedef __attribute__((ext_vector_type(8))) short bf16x8;   // 8 bf16 in 4 VGPRs

__device__ __forceinline__ float bf2f(unsigned short u) {
  union { unsigned int i; float f; } c; c.i = ((unsigned int)u) << 16; return c.f;
}
__device__ __forceinline__ unsigned short f2bf(float f) {   // RNE
  union { float f; unsigned int i; } c; c.f = f;
  unsigned int u = c.i;
  return (unsigned short)((u + 0x7fffu + ((u >> 16) & 1u)) >> 16);
}
__device__ __forceinline__ float sigmoid_fast(float x) { return 1.0f / (1.0f + __expf(-x)); }
__device__ __forceinline__ float tanh_fast(float x) {
  float a = fabsf(x);
  float e = __expf(2.0f * a);
  return copysignf(1.0f - 2.0f / (e + 1.0f), x);
}
__device__ __forceinline__ f32x4 mfma16(bf16x8 a, bf16x8 b, f32x4 c) {
  return __builtin_amdgcn_mfma_f32_16x16x32_bf16(a, b, c, 0, 0, 0);
}
// ---- device-coherent primitives (relaxed agent scope, R5/R6-proven) ----
__device__ __forceinline__ unsigned long long ld_u64_agent(const unsigned long long* p) {
  return __hip_atomic_load(p, __ATOMIC_RELAXED, __HIP_MEMORY_SCOPE_AGENT);
}
__device__ __forceinline__ void st_u64_agent(unsigned long long* p, unsigned long long v) {
  __hip_atomic_store(p, v, __ATOMIC_RELAXED, __HIP_MEMORY_SCOPE_AGENT);
}
__device__ __forceinline__ unsigned int ld_u32_agent(const unsigned int* p) {
  return __hip_atomic_load(p, __ATOMIC_RELAXED, __HIP_MEMORY_SCOPE_AGENT);
}
__device__ __forceinline__ void st_u32_agent(unsigned int* p, unsigned int v) {
  __hip_atomic_store(p, v, __ATOMIC_RELAXED, __HIP_MEMORY_SCOPE_AGENT);
}

// ---------------- ws layout (bytes) ----------------
// R7: per-(block,wave) flags [4][32][2], each on its own 256B line, posted
// right after that wave's own vmcnt(0) drain (no pre-flag barrier).
// Payloads in block-major contiguous 1KB chunks: chunk bh = [16 rows][32 cols].
#define SLOT_STRIDE 64       // u32s per flag slot = 256 B
#define OFF_HB2   0          // bf16 Hb2[2][4][32][16][32] = 256 KB
#define OFF_RH2   262144     // bf16 rh2[4][32][16][32]   = 128 KB
#define OFF_HF    393216     // f32 Hf[64][1024]          = 256 KB
#define OFF_SLOTS 655360     // u32 [4][32][2] x 256 B    = 64 KB
#define OFF_WR    1704960
#define OFF_WZ    3802112
#define OFF_WC    5899264
#define OFF_WX    7996416
#define OFF_XP    11142144

// ============================================================================
// convert: fp32 weights -> bf16, pre-swizzled into MFMA B-fragment order.
// ============================================================================
__global__ void convert_kernel(const float* __restrict__ Whr, const float* __restrict__ Whz,
                               const float* __restrict__ Whc,
                               const float* __restrict__ Wxr, const float* __restrict__ Wxz,
                               const float* __restrict__ Wxc,
                               unsigned short* __restrict__ Wr_swz, unsigned short* __restrict__ Wz_swz,
                               unsigned short* __restrict__ Wc_swz, unsigned short* __restrict__ Wx_swz) {
  long idx = (long)blockIdx.x * blockDim.x + threadIdx.x;
  const long NH = (long)HD * HD;
  if (idx < 3 * NH) {
    int m = (int)(idx >> 20);
    int t = (int)(idx & (NH - 1));
    int k = t >> 10, j = t & 1023;
    const float* src = (m == 0) ? Whr : (m == 1) ? Whz : Whc;
    unsigned short* dst = (m == 0) ? Wr_swz : (m == 1) ? Wz_swz : Wc_swz;
    int jt = j >> 4, n = j & 15, kt = k >> 5, q = (k >> 3) & 3, i = k & 7;
    dst[((long)(jt * 32 + kt) * 64 + (q * 16 + n)) * 8 + i] = f2bf(src[(long)k * HD + j]);
  } else {
    long t = idx - 3 * NH;
    if (t < (long)E_DIM * NGATE) {
      int e  = (int)(t / NGATE);
      int jg = (int)(t - (long)e * NGATE);
      int jt = jg >> 4, n = jg & 15, kt = e >> 5, q = (e >> 3) & 3, i = e & 7;
      int gate = jg >> 10, jj = jg & 1023;
      const float* src = (gate == 0) ? Wxr : (gate == 1) ? Wxz : Wxc;
      Wx_swz[((long)(jt * 16 + kt) * 64 + (q * 16 + n)) * 8 + i] = f2bf(src[(long)e * HD + jj]);
    }
  }
}

// ============================================================================
// embed + X-projection -> Xp[s][g][jglob][16b] (bf16, bias folded in).
// ============================================================================
__launch_bounds__(256, 2)
__global__ void embed_kernel(const int* __restrict__ tokens,
                             const float* __restrict__ Emb,
                             const unsigned short* __restrict__ Wx_swz,
                             const float* __restrict__ b_r, const float* __restrict__ b_z,
                             const float* __restrict__ b_c,
                             unsigned short* __restrict__ Xp) {
  __shared__ unsigned short xl[B_SZ * E_DIM];   // 64 KB
  const int s = blockIdx.y;
  const int slab = blockIdx.x;                  // 0..47
  const int tid = threadIdx.x;
  for (int it = 0; it < 32; ++it) {
    int task = tid + 256 * it;
    int row = task >> 7;
    int f = task & 127;
    int tok = tokens[row * S_LEN + s];
    float4 v = *(const float4*)(Emb + (long)tok * E_DIM + f * 4);
    int sw = (f >> 1) ^ (row & 7);
    unsigned short* p = xl + row * E_DIM + sw * 8 + (f & 1) * 4;
    p[0] = f2bf(v.x); p[1] = f2bf(v.y); p[2] = f2bf(v.z); p[3] = f2bf(v.w);
  }
  __syncthreads();
  const int lane = tid & 63, wave = tid >> 6;
  const int n = lane & 15, q = lane >> 4;
  const int jt_glob = slab * 4 + wave;
  f32x4 acc[4];
  #pragma unroll
  for (int bt = 0; bt < 4; ++bt) { acc[bt][0]=0.f; acc[bt][1]=0.f; acc[bt][2]=0.f; acc[bt][3]=0.f; }
  for (int kt = 0; kt < 16; ++kt) {
    bf16x8 bfrag = *(const bf16x8*)(Wx_swz + ((long)(jt_glob * 16 + kt) * 64 + lane) * 8);
    #pragma unroll
    for (int bt = 0; bt < 4; ++bt) {
      int row = bt * 16 + n;
      int chunk = (kt * 4 + q) ^ (row & 7);
      bf16x8 afrag = *(const bf16x8*)(xl + row * E_DIM + chunk * 8);
      acc[bt] = mfma16(afrag, bfrag, acc[bt]);
    }
  }
  const int jglob = jt_glob * 16 + n;
  const int gate = jglob >> 10, jj = jglob & 1023;
  const float bias = (gate == 0 ? b_r : gate == 1 ? b_z : b_c)[jj];
  #pragma unroll
  for (int bt = 0; bt < 4; ++bt) {              // bt == batch group
    unsigned int lo = (unsigned)f2bf(acc[bt][0] + bias) | ((unsigned)f2bf(acc[bt][1] + bias) << 16);
    unsigned int hi = (unsigned)f2bf(acc[bt][2] + bias) | ((unsigned)f2bf(acc[bt][3] + bias) << 16);
    uint2 pk; pk.x = lo; pk.y = hi;             // rows 4q..4q+3 within group
    *(uint2*)(Xp + (((long)s * 4 + bt) * NGATE + jglob) * 16 + q * 4) = pk;
  }
}

// ============================================================================
// persistent GRU (R7): overlapped serial chain.
// Per step (3 barriers, free-running tail):
//   A: r-MFMA -> bar1 -> (w0,1) reduce r, gate, rh chunk store, OWN vmcnt(0),
//      OWN flag (seq)          [no pre-flag barrier; per-wave flags]
//   z-MFMA + red-write (all waves)  <- runs inside the rh-exchange flight
//   per-wave poll of its 8 producers x 2 flags -> issue rh loads -> bar2
//   (w2,3) reduce z -> zbuf
//   c-MFMA -> bar3 -> (w0,1) reduce c, H update, H chunk store, drain,
//      flag (seq+1)
//   tail: Xp prefetch issue -> per-wave poll (seq+1) -> H loads -> next step
// LDS slot discipline (red[4][6]): r->0,1  z->2,3  c->4,5 removes the
// end-of-step barrier (hazard audit in session notes: bar3/bar1 transitivity).
// ============================================================================
__launch_bounds__(256, 1)
__global__ void gru_kernel(const unsigned short* __restrict__ Xp,
                           const unsigned short* __restrict__ Wr_swz,
                           const unsigned short* __restrict__ Wz_swz,
                           const unsigned short* __restrict__ Wc_swz,
                           unsigned short* __restrict__ Hb2,    // [2][4][32][16][32] bf16
                           float* __restrict__ Hf,              // [64][1024] f32 (last step)
                           unsigned short* __restrict__ rh2,    // [4][32][16][32] bf16
                           unsigned int* __restrict__ slots) {  // [4][32][2] padded x64
  __shared__ float red[4][6][256];              // 24 KB [src wave][slot][...]
  __shared__ float zbuf[2][256];                // 2 KB
  __shared__ unsigned short ldsT[2][256];       // 1 KB transpose staging
  __shared__ float hmaster[16 * 32];            // 2 KB fp32 H master [row][col]

  const int tid = threadIdx.x;
  const int lane = tid & 63, w = tid >> 6;
  const int n = lane & 15, q = lane >> 4;
  const int blk = blockIdx.x;                   // 0..127
  const int g  = blk & 3;                       // batch group (rows 16g..16g+15)
  const int bh = blk >> 2;                      // j-slice [32bh, 32bh+32), bh 0..31
  const int row_t = lane >> 2, word_t = lane & 3;

  // ---- weights -> registers: per-wave K-quarter (kt = w*8..w*8+7), 2 j-tiles ----
  bf16x8 wr_reg[2][8], wz_reg[2][8], wc_reg[2][8];
  #pragma unroll
  for (int jt = 0; jt < 2; ++jt)
    #pragma unroll
    for (int t = 0; t < 8; ++t) {
      long o = ((long)((2 * bh + jt) * 32 + w * 8 + t)) * 512 + lane * 8;
      wr_reg[jt][t] = *(const bf16x8*)(Wr_swz + o);
      wz_reg[jt][t] = *(const bf16x8*)(Wz_swz + o);
      wc_reg[jt][t] = *(const bf16x8*)(Wc_swz + o);
    }
  for (int i = tid; i < 512; i += 256) hmaster[i] = 0.f;   // H0 = 0
  __syncthreads();

  unsigned int* gslots = slots + g * 64 * SLOT_STRIDE;
  unsigned int* myflag = gslots + (bh * 2 + w) * SLOT_STRIDE;          // waves 0,1
  const unsigned int* pollp =
      gslots + (((w * 8 + (lane >> 1)) * 2) + (lane & 1)) * SLOT_STRIDE; // lane<16

  unsigned long long* rh_u64 = (unsigned long long*)rh2;
  unsigned long long* hb_u64 = (unsigned long long*)Hb2;

  // Xp pointers: wave w's phase-A/z tile = (gate w>>1, jt w&1); waves 0,1 c-tile w
  const int gate_w = w >> 1, jt_w = w & 1;
  const long xp_stride = (long)4 * NGATE * 16;   // shorts per step
  const unsigned short* xp1_p = Xp + (((long)g * NGATE) + gate_w * HD + bh * 32 + jt_w * 16 + n) * 16 + q * 4;
  const unsigned short* xpc_p = Xp + (((long)g * NGATE) + 2 * HD + bh * 32 + w * 16 + n) * 16 + q * 4;

  uint2 xp1 = *(const uint2*)xp1_p;              // step 0
  uint2 xpc; xpc.x = 0; xpc.y = 0;
  if (w < 2) xpc = *(const uint2*)xpc_p;

  // producer store offset (waves 0,1): chunk bh, row row_t, cols w*16+word_t*4
  const long my_off = (long)(g * 32 + bh) * 128 + row_t * 8 + w * 4 + word_t;
  // consumer per-lane offset within a chunk: row n, cols q*8..q*8+8
  const long ld_off = (long)n * 8 + q * 2;
  const long grp128 = (long)g * 32 * 128;

  // H chunk data in regs; H0 = 0 (no loads, no memset dependency on Hb2)
  unsigned long long a0[8], a1[8];
  #pragma unroll
  for (int t = 0; t < 8; ++t) { a0[t] = 0ull; a1[t] = 0ull; }

  int cur = 0;
  unsigned int seq = 1;

  for (int s = 0; s < S_LEN; ++s) {
    // ============ phase A: r only ============
    f32x4 aR0, aR1;
    aR0[0]=0.f;aR0[1]=0.f;aR0[2]=0.f;aR0[3]=0.f; aR1 = aR0;
    #pragma unroll
    for (int t = 0; t < 8; ++t) {
      union { unsigned long long u[2]; bf16x8 v; } af;
      af.u[0] = a0[t]; af.u[1] = a1[t];
      aR0 = mfma16(af.v, wr_reg[0][t], aR0);
      aR1 = mfma16(af.v, wr_reg[1][t], aR1);
    }
    *(f32x4*)&red[w][0][lane * 4] = aR0;
    *(f32x4*)&red[w][1][lane * 4] = aR1;
    __syncthreads();                              // bar1
    if (w < 2) {                                  // reduce r tile w -> rh store
      f32x4 acc = *(const f32x4*)&red[0][w][lane * 4];
      #pragma unroll
      for (int k = 1; k < 4; ++k) { f32x4 p = *(const f32x4*)&red[k][w][lane * 4]; acc += p; }
      #pragma unroll
      for (int r_ = 0; r_ < 4; ++r_) {
        float xpv = bf2f((unsigned short)(((r_ < 2) ? xp1.x : xp1.y) >> ((r_ & 1) * 16)));
        float rv = sigmoid_fast(acc[r_] + xpv);
        ldsT[w][(q * 4 + r_) * 16 + n] = f2bf(rv * hmaster[(q * 4 + r_) * 32 + w * 16 + n]);
      }
      asm volatile("s_waitcnt lgkmcnt(0)" ::: "memory");
      unsigned long long pay = *(const unsigned long long*)(&ldsT[w][row_t * 16 + word_t * 4]);
      st_u64_agent(rh_u64 + my_off, pay);
      asm volatile("s_waitcnt vmcnt(0)" ::: "memory");   // own payload at LLC
      if (lane == 0) st_u32_agent(myflag, seq);          // own flag, immediately
    }
    // ---- z-MFMA inside the rh-exchange flight (all waves) ----
    f32x4 aZ0, aZ1;
    aZ0[0]=0.f;aZ0[1]=0.f;aZ0[2]=0.f;aZ0[3]=0.f; aZ1 = aZ0;
    #pragma unroll
    for (int t = 0; t < 8; ++t) {
      union { unsigned long long u[2]; bf16x8 v; } af;
      af.u[0] = a0[t]; af.u[1] = a1[t];
      aZ0 = mfma16(af.v, wz_reg[0][t], aZ0);
      aZ1 = mfma16(af.v, wz_reg[1][t], aZ1);
    }
    *(f32x4*)&red[w][2][lane * 4] = aZ0;
    *(f32x4*)&red[w][3][lane * 4] = aZ1;
    // ---- per-wave poll of own 8 producers x 2 wave-flags, then rh loads ----
    if (lane < 16) { while (ld_u32_agent(pollp) < seq) {} }
    asm volatile("" ::: "memory");
    unsigned long long c0[8], c1[8];
    #pragma unroll
    for (int t = 0; t < 8; ++t) {
      const unsigned long long* p =
          (const unsigned long long*)rh2 + grp128 + (long)(w * 8 + t) * 128 + ld_off;
      c0[t] = ld_u64_agent(p);
      c1[t] = ld_u64_agent(p + 1);
    }
    __syncthreads();                              // bar2 (z partials visible)
    if (w >= 2) {                                 // reduce z tile w-2 -> zbuf
      f32x4 accz = *(const f32x4*)&red[0][w][lane * 4];
      #pragma unroll
      for (int k = 1; k < 4; ++k) { f32x4 p = *(const f32x4*)&red[k][w][lane * 4]; accz += p; }
      #pragma unroll
      for (int r_ = 0; r_ < 4; ++r_) {
        float xpv = bf2f((unsigned short)(((r_ < 2) ? xp1.x : xp1.y) >> ((r_ & 1) * 16)));
        zbuf[w - 2][(q * 4 + r_) * 16 + n] = sigmoid_fast(accz[r_] + xpv);
      }
    }
    // ============ phase B: c ============
    f32x4 cA, cB;
    cA[0]=0.f;cA[1]=0.f;cA[2]=0.f;cA[3]=0.f; cB = cA;
    #pragma unroll
    for (int t = 0; t < 8; ++t) {
      union { unsigned long long u[2]; bf16x8 v; } af;
      af.u[0] = c0[t]; af.u[1] = c1[t];
      cA = mfma16(af.v, wc_reg[0][t], cA);
      cB = mfma16(af.v, wc_reg[1][t], cB);
    }
    *(f32x4*)&red[w][4][lane * 4] = cA;
    *(f32x4*)&red[w][5][lane * 4] = cB;
    __syncthreads();                              // bar3
    if (w < 2) {                                  // reduce c tile w -> H update
      f32x4 acc2 = *(const f32x4*)&red[0][4 + w][lane * 4];
      #pragma unroll
      for (int k = 1; k < 4; ++k) { f32x4 p = *(const f32x4*)&red[k][4 + w][lane * 4]; acc2 += p; }
      #pragma unroll
      for (int r_ = 0; r_ < 4; ++r_) {
        float xpv = bf2f((unsigned short)(((r_ < 2) ? xpc.x : xpc.y) >> ((r_ & 1) * 16)));
        float cv = tanh_fast(acc2[r_] + xpv);
        float z  = zbuf[w][(q * 4 + r_) * 16 + n];
        float h0 = hmaster[(q * 4 + r_) * 32 + w * 16 + n];
        float hn = z * h0 + (1.0f - z) * cv;
        hmaster[(q * 4 + r_) * 32 + w * 16 + n] = hn;
        ldsT[w][(q * 4 + r_) * 16 + n] = f2bf(hn);
        if (s == S_LEN - 1)
          Hf[(long)(g * 16 + q * 4 + r_) * HD + bh * 32 + w * 16 + n] = hn;
      }
      asm volatile("s_waitcnt lgkmcnt(0)" ::: "memory");
      unsigned long long pay = *(const unsigned long long*)(&ldsT[w][row_t * 16 + word_t * 4]);
      st_u64_agent(hb_u64 + (long)(cur ^ 1) * 16384 + my_off, pay);
      asm volatile("s_waitcnt vmcnt(0)" ::: "memory");   // own payload at LLC
      if (lane == 0) st_u32_agent(myflag, seq + 1);      // own flag, immediately
    }
    // ============ free-running tail: prefetch + poll + H loads ============
    if (s < S_LEN - 1) {
      uint2 xp1n = *(const uint2*)(xp1_p + (long)(s + 1) * xp_stride);  // issue early
      uint2 xpcn; xpcn.x = 0; xpcn.y = 0;
      if (w < 2) xpcn = *(const uint2*)(xpc_p + (long)(s + 1) * xp_stride);
      if (lane < 16) { while (ld_u32_agent(pollp) < seq + 1) {} }
      asm volatile("" ::: "memory");
      const unsigned long long* hb =
          (const unsigned long long*)Hb2 + (long)(cur ^ 1) * 16384 + grp128;
      #pragma unroll
      for (int t = 0; t < 8; ++t) {
        const unsigned long long* p = hb + (long)(w * 8 + t) * 128 + ld_off;
        a0[t] = ld_u64_agent(p);
        a1[t] = ld_u64_agent(p + 1);
      }
      xp1 = xp1n;
      if (w < 2) xpc = xpcn;
    }
    seq += 2;
    cur ^= 1;
  }
}

// ============================================================================
// logits + softmax: one wave per batch row
// ============================================================================
__global__ void logits_kernel(const float* __restrict__ Hf, const float* __restrict__ Whq,
                              const float* __restrict__ bq, float* __restrict__ out) {
  const int b = blockIdx.x;
  const int lane = threadIdx.x;   // 64
  float acc[O_DIM];
  #pragma unroll
  for (int o = 0; o < O_DIM; ++o) acc[o] = 0.f;
  for (int k = lane; k < HD; k += 64) {
    float h = Hf[(long)b * HD + k];
    #pragma unroll
    for (int o = 0; o < O_DIM; ++o) acc[o] += h * Whq[(long)k * O_DIM + o];
  }
  #pragma unroll
  for (int o = 0; o < O_DIM; ++o) {
    #pragma unroll
    for (int off = 32; off > 0; off >>= 1) acc[o] += __shfl_down(acc[o], off, 64);
  }
  if (lane == 0) {
    float lg[O_DIM], m = -1e30f, sum = 0.f;
    #pragma unroll
    for (int o = 0; o < O_DIM; ++o) { lg[o] = acc[o] + bq[o]; m = fmaxf(m, lg[o]); }
    #pragma unroll
    for (int o = 0; o < O_DIM; ++o) { lg[o] = __expf(lg[o] - m); sum += lg[o]; }
    float inv = 1.0f / sum;
    #pragma unroll
    for (int o = 0; o < O_DIM; ++o) out[(long)b * O_DIM + o] = lg[o] * inv;
  }
}

// ============================================================================
extern "C" void kernel_launch(void* const* d_in, const int* in_sizes, int n_in,
                              void* d_out, int out_size, void* d_ws, size_t ws_size,
                              hipStream_t stream) {
  const int*   tokens = (const int*)d_in[0];
  const float* Emb = (const float*)d_in[1];
  const float* Wxr = (const float*)d_in[2];
  const float* Whr = (const float*)d_in[3];
  const float* br  = (const float*)d_in[4];
  const float* Wxz = (const float*)d_in[5];
  const float* Whz = (const float*)d_in[6];
  const float* bz  = (const float*)d_in[7];
  const float* Wxc = (const float*)d_in[8];
  const float* Whc = (const float*)d_in[9];
  const float* bc  = (const float*)d_in[10];
  const float* Whq = (const float*)d_in[11];
  const float* bq  = (const float*)d_in[12];

  char* ws = (char*)d_ws;
  unsigned short* Hb2    = (unsigned short*)(ws + OFF_HB2);
  unsigned short* rh2    = (unsigned short*)(ws + OFF_RH2);
  float*          Hf     = (float*)(ws + OFF_HF);
  unsigned int*   slots  = (unsigned int*)(ws + OFF_SLOTS);
  unsigned short* Wr_swz = (unsigned short*)(ws + OFF_WR);
  unsigned short* Wz_swz = (unsigned short*)(ws + OFF_WZ);
  unsigned short* Wc_swz = (unsigned short*)(ws + OFF_WC);
  unsigned short* Wx_swz = (unsigned short*)(ws + OFF_WX);
  unsigned short* Xp     = (unsigned short*)(ws + OFF_XP);

  // only the flags need zeroing (H0 handled in-register; buffers write-before-read)
  hipMemsetAsync(ws + OFF_SLOTS, 0, 65536, stream);

  convert_kernel<<<18432, 256, 0, stream>>>(Whr, Whz, Whc, Wxr, Wxz, Wxc,
                                            Wr_swz, Wz_swz, Wc_swz, Wx_swz);
  embed_kernel<<<dim3(48, S_LEN), 256, 0, stream>>>(tokens, Emb, Wx_swz, br, bz, bc, Xp);
  gru_kernel<<<128, 256, 0, stream>>>(Xp, Wr_swz, Wz_swz, Wc_swz,
                                      Hb2, Hf, rh2, slots);
  logits_kernel<<<B_SZ, 64, 0, stream>>>(Hf, Whq, bq, (float*)d_out);
}

// Round 5
// 3272.379 us; speedup vs baseline: 2.5877x; 1.0856x over previous
//
#include <hip/hip_runtime.h>
#include <stdint.h>

// ---------------- problem constants ----------------
#define S_LEN 512
#define B_SZ  64
#define E_DIM 512
#define HD    1024
#define NGATE 3072   // 3*HD (r,z,c)
#define O_DIM 10

typedef __attribute__((ext_vector_type(4))) float f32x4;
typedef __attribute__((ext_vector_type(8))) short bf16x8;   // 8 bf16 in 4 VGPRs

__device__ __forceinline__ float bf2f(unsigned short u) {
  union { unsigned int i; float f; } c; c.i = ((unsigned int)u) << 16; return c.f;
}
__device__ __forceinline__ unsigned short f2bf(float f) {   // RNE
  union { float f; unsigned int i; } c; c.f = f;
  unsigned int u = c.i;
  return (unsigned short)((u + 0x7fffu + ((u >> 16) & 1u)) >> 16);
}
__device__ __forceinline__ float sigmoid_fast(float x) { return 1.0f / (1.0f + __expf(-x)); }
__device__ __forceinline__ float tanh_fast(float x) {
  float a = fabsf(x);
  float e = __expf(2.0f * a);
  return copysignf(1.0f - 2.0f / (e + 1.0f), x);
}
__device__ __forceinline__ f32x4 mfma16(bf16x8 a, bf16x8 b, f32x4 c) {
  return __builtin_amdgcn_mfma_f32_16x16x32_bf16(a, b, c, 0, 0, 0);
}
// ---- device-coherent primitives (relaxed agent scope, R5/R6/R7-proven) ----
__device__ __forceinline__ unsigned long long ld_u64_agent(const unsigned long long* p) {
  return __hip_atomic_load(p, __ATOMIC_RELAXED, __HIP_MEMORY_SCOPE_AGENT);
}
__device__ __forceinline__ unsigned int ld_u32_agent(const unsigned int* p) {
  return __hip_atomic_load(p, __ATOMIC_RELAXED, __HIP_MEMORY_SCOPE_AGENT);
}
__device__ __forceinline__ void st_u32_agent(unsigned int* p, unsigned int v) {
  __hip_atomic_store(p, v, __ATOMIC_RELAXED, __HIP_MEMORY_SCOPE_AGENT);
}

// ---------------- ws layout (bytes) ----------------
// R8: 4-wave produce, per-(block,wave) flags [4][32][4] each on its own 256B
// line. Payload chunks unchanged: [16 rows][32 cols] bf16 = 1KB per block.
#define SLOT_STRIDE 64       // u32s per flag slot = 256 B
#define OFF_HB2   0          // bf16 Hb2[2][4][32][16][32] = 256 KB
#define OFF_RH2   262144     // bf16 rh2[4][32][16][32]   = 128 KB
#define OFF_HF    393216     // f32 Hf[64][1024]          = 256 KB
#define OFF_SLOTS 655360     // u32 [4][32][4] x 256 B    = 128 KB
#define OFF_WR    1704960
#define OFF_WZ    3802112
#define OFF_WC    5899264
#define OFF_WX    7996416
#define OFF_XP    11142144

// ============================================================================
// convert: fp32 weights -> bf16, pre-swizzled into MFMA B-fragment order.
// ============================================================================
__global__ void convert_kernel(const float* __restrict__ Whr, const float* __restrict__ Whz,
                               const float* __restrict__ Whc,
                               const float* __restrict__ Wxr, const float* __restrict__ Wxz,
                               const float* __restrict__ Wxc,
                               unsigned short* __restrict__ Wr_swz, unsigned short* __restrict__ Wz_swz,
                               unsigned short* __restrict__ Wc_swz, unsigned short* __restrict__ Wx_swz) {
  long idx = (long)blockIdx.x * blockDim.x + threadIdx.x;
  const long NH = (long)HD * HD;
  if (idx < 3 * NH) {
    int m = (int)(idx >> 20);
    int t = (int)(idx & (NH - 1));
    int k = t >> 10, j = t & 1023;
    const float* src = (m == 0) ? Whr : (m == 1) ? Whz : Whc;
    unsigned short* dst = (m == 0) ? Wr_swz : (m == 1) ? Wz_swz : Wc_swz;
    int jt = j >> 4, n = j & 15, kt = k >> 5, q = (k >> 3) & 3, i = k & 7;
    dst[((long)(jt * 32 + kt) * 64 + (q * 16 + n)) * 8 + i] = f2bf(src[(long)k * HD + j]);
  } else {
    long t = idx - 3 * NH;
    if (t < (long)E_DIM * NGATE) {
      int e  = (int)(t / NGATE);
      int jg = (int)(t - (long)e * NGATE);
      int jt = jg >> 4, n = jg & 15, kt = e >> 5, q = (e >> 3) & 3, i = e & 7;
      int gate = jg >> 10, jj = jg & 1023;
      const float* src = (gate == 0) ? Wxr : (gate == 1) ? Wxz : Wxc;
      Wx_swz[((long)(jt * 16 + kt) * 64 + (q * 16 + n)) * 8 + i] = f2bf(src[(long)e * HD + jj]);
    }
  }
}

// ============================================================================
// embed + X-projection -> Xp[s][g][jglob][16b] (bf16, bias folded in).
// ============================================================================
__launch_bounds__(256, 2)
__global__ void embed_kernel(const int* __restrict__ tokens,
                             const float* __restrict__ Emb,
                             const unsigned short* __restrict__ Wx_swz,
                             const float* __restrict__ b_r, const float* __restrict__ b_z,
                             const float* __restrict__ b_c,
                             unsigned short* __restrict__ Xp) {
  __shared__ unsigned short xl[B_SZ * E_DIM];   // 64 KB
  const int s = blockIdx.y;
  const int slab = blockIdx.x;                  // 0..47
  const int tid = threadIdx.x;
  for (int it = 0; it < 32; ++it) {
    int task = tid + 256 * it;
    int row = task >> 7;
    int f = task & 127;
    int tok = tokens[row * S_LEN + s];
    float4 v = *(const float4*)(Emb + (long)tok * E_DIM + f * 4);
    int sw = (f >> 1) ^ (row & 7);
    unsigned short* p = xl + row * E_DIM + sw * 8 + (f & 1) * 4;
    p[0] = f2bf(v.x); p[1] = f2bf(v.y); p[2] = f2bf(v.z); p[3] = f2bf(v.w);
  }
  __syncthreads();
  const int lane = tid & 63, wave = tid >> 6;
  const int n = lane & 15, q = lane >> 4;
  const int jt_glob = slab * 4 + wave;
  f32x4 acc[4];
  #pragma unroll
  for (int bt = 0; bt < 4; ++bt) { acc[bt][0]=0.f; acc[bt][1]=0.f; acc[bt][2]=0.f; acc[bt][3]=0.f; }
  for (int kt = 0; kt < 16; ++kt) {
    bf16x8 bfrag = *(const bf16x8*)(Wx_swz + ((long)(jt_glob * 16 + kt) * 64 + lane) * 8);
    #pragma unroll
    for (int bt = 0; bt < 4; ++bt) {
      int row = bt * 16 + n;
      int chunk = (kt * 4 + q) ^ (row & 7);
      bf16x8 afrag = *(const bf16x8*)(xl + row * E_DIM + chunk * 8);
      acc[bt] = mfma16(afrag, bfrag, acc[bt]);
    }
  }
  const int jglob = jt_glob * 16 + n;
  const int gate = jglob >> 10, jj = jglob & 1023;
  const float bias = (gate == 0 ? b_r : gate == 1 ? b_z : b_c)[jj];
  #pragma unroll
  for (int bt = 0; bt < 4; ++bt) {              // bt == batch group
    unsigned int lo = (unsigned)f2bf(acc[bt][0] + bias) | ((unsigned)f2bf(acc[bt][1] + bias) << 16);
    unsigned int hi = (unsigned)f2bf(acc[bt][2] + bias) | ((unsigned)f2bf(acc[bt][3] + bias) << 16);
    uint2 pk; pk.x = lo; pk.y = hi;             // rows 4q..4q+3 within group
    *(uint2*)(Xp + (((long)s * 4 + bt) * NGATE + jglob) * 16 + q * 4) = pk;
  }
}

// ============================================================================
// persistent GRU (R8): R7 protocol + 4-wave transpose-free produce.
//   - produce mapping: wave w owns rows [4w,4w+4) x 32 cols. Each lane
//     reduces 2 values (8 ds_read_b32), gates 2, stores ONE u32 directly at
//     its final chunk address (no ldsT, no lgkmcnt round-trip).
//   - 4 flags/block (one per wave, posted after own vmcnt(0)); consumers
//     poll 32 flags (8 producers x 4 waves), one per lane<32.
//   - z-reduce keeps old tile mapping (latency-hidden), zbuf now row-major.
//   - barriers/hazards identical to R7 (bar1/bar2/bar3 transitivity).
// ============================================================================
__launch_bounds__(256, 1)
__global__ void gru_kernel(const unsigned short* __restrict__ Xp,
                           const unsigned short* __restrict__ Wr_swz,
                           const unsigned short* __restrict__ Wz_swz,
                           const unsigned short* __restrict__ Wc_swz,
                           unsigned short* __restrict__ Hb2,    // [2][4][32][16][32] bf16
                           float* __restrict__ Hf,              // [64][1024] f32 (last step)
                           unsigned short* __restrict__ rh2,    // [4][32][16][32] bf16
                           unsigned int* __restrict__ slots) {  // [4][32][4] padded x64
  __shared__ float red[4][6][256];              // 24 KB [src wave][slot][...]
  __shared__ float zbuf[16 * 32];               // 2 KB row-major [row][col]
  __shared__ float hmaster[16 * 32];            // 2 KB fp32 H master [row][col]

  const int tid = threadIdx.x;
  const int lane = tid & 63, w = tid >> 6;
  const int n = lane & 15, q = lane >> 4;
  const int blk = blockIdx.x;                   // 0..127
  const int g  = blk & 3;                       // batch group (rows 16g..16g+15)
  const int bh = blk >> 2;                      // j-slice [32bh, 32bh+32), bh 0..31

  // produce mapping: wave w -> rows [4w,4w+4); lane -> (row 4w+rr, cols pc,pc+1)
  const int rr = lane >> 4;                     // 0..3
  const int m  = lane & 15;
  const int prow = 4 * w + rr;                  // 0..15
  const int pc = 2 * m;                         // 0..30 (even)
  const int t0 = pc >> 4;                       // tile (same for pc, pc+1)
  const int n0 = pc & 15;

  // ---- weights -> registers: per-wave K-quarter (kt = w*8..w*8+7), 2 j-tiles ----
  bf16x8 wr_reg[2][8], wz_reg[2][8], wc_reg[2][8];
  #pragma unroll
  for (int jt = 0; jt < 2; ++jt)
    #pragma unroll
    for (int t = 0; t < 8; ++t) {
      long o = ((long)((2 * bh + jt) * 32 + w * 8 + t)) * 512 + lane * 8;
      wr_reg[jt][t] = *(const bf16x8*)(Wr_swz + o);
      wz_reg[jt][t] = *(const bf16x8*)(Wz_swz + o);
      wc_reg[jt][t] = *(const bf16x8*)(Wc_swz + o);
    }
  for (int i = tid; i < 512; i += 256) hmaster[i] = 0.f;   // H0 = 0
  __syncthreads();

  unsigned int* gslots = slots + g * 128 * SLOT_STRIDE;    // 32 blocks x 4 waves
  unsigned int* myflag = gslots + (bh * 4 + w) * SLOT_STRIDE;
  const unsigned int* pollp =
      gslots + ((w * 8 + (lane >> 2)) * 4 + (lane & 3)) * SLOT_STRIDE;  // lane<32

  // Xp addresses (layout: [s][g][jglob][row0..15])
  const long xp_step = (long)4 * NGATE * 16;    // shorts per step
  const unsigned short* xr_p = Xp + ((long)g * NGATE + bh * 32 + pc) * 16 + prow;
  const unsigned short* xc_p = Xp + ((long)g * NGATE + 2 * HD + bh * 32 + pc) * 16 + prow;
  const unsigned short* xz_p = Xp + ((long)g * NGATE + HD + bh * 32 + (w & 1) * 16 + n) * 16 + q * 4;

  unsigned short xr0 = xr_p[0],  xr1 = xr_p[16];
  unsigned short xc0 = xc_p[0],  xc1 = xc_p[16];
  uint2 xz; xz.x = 0; xz.y = 0;
  if (w >= 2) xz = *(const uint2*)xz_p;

  // producer store offset (u32 units): chunk (g,bh), row prow, cols pc..pc+1
  const long my32 = (long)(g * 32 + bh) * 256 + (long)prow * 16 + m;
  // consumer per-lane offset within a chunk (u64 units): row n, cols q*8..q*8+8
  const long ld64 = (long)n * 8 + q * 2;
  const long grp64 = (long)g * 4096;            // group base in u64 units

  unsigned int* rh_u32 = (unsigned int*)rh2;
  unsigned int* hb_u32 = (unsigned int*)Hb2;

  // H chunk data in regs; H0 = 0
  unsigned long long a0[8], a1[8];
  #pragma unroll
  for (int t = 0; t < 8; ++t) { a0[t] = 0ull; a1[t] = 0ull; }

  int cur = 0;
  unsigned int seq = 1;

  for (int s = 0; s < S_LEN; ++s) {
    // ============ phase A: r-MFMA ============
    f32x4 aR0, aR1;
    aR0[0]=0.f;aR0[1]=0.f;aR0[2]=0.f;aR0[3]=0.f; aR1 = aR0;
    #pragma unroll
    for (int t = 0; t < 8; ++t) {
      union { unsigned long long u[2]; bf16x8 v; } af;
      af.u[0] = a0[t]; af.u[1] = a1[t];
      aR0 = mfma16(af.v, wr_reg[0][t], aR0);
      aR1 = mfma16(af.v, wr_reg[1][t], aR1);
    }
    *(f32x4*)&red[w][0][lane * 4] = aR0;
    *(f32x4*)&red[w][1][lane * 4] = aR1;
    __syncthreads();                              // bar1
    // ---- 4-wave produce rh: lane -> (prow, pc), (prow, pc+1) ----
    {
      float v0 = 0.f, v1 = 0.f;
      #pragma unroll
      for (int k = 0; k < 4; ++k) {
        v0 += red[k][t0][(w * 16 + n0) * 4 + rr];
        v1 += red[k][t0][(w * 16 + n0 + 1) * 4 + rr];
      }
      float r0 = sigmoid_fast(v0 + bf2f(xr0)) * hmaster[prow * 32 + pc];
      float r1 = sigmoid_fast(v1 + bf2f(xr1)) * hmaster[prow * 32 + pc + 1];
      unsigned int pay = (unsigned)f2bf(r0) | ((unsigned)f2bf(r1) << 16);
      st_u32_agent(rh_u32 + my32, pay);
      asm volatile("s_waitcnt vmcnt(0)" ::: "memory");   // own payload at LLC
      if (lane == 0) st_u32_agent(myflag, seq);
    }
    // ---- z-MFMA inside the rh-exchange flight (all waves) ----
    f32x4 aZ0, aZ1;
    aZ0[0]=0.f;aZ0[1]=0.f;aZ0[2]=0.f;aZ0[3]=0.f; aZ1 = aZ0;
    #pragma unroll
    for (int t = 0; t < 8; ++t) {
      union { unsigned long long u[2]; bf16x8 v; } af;
      af.u[0] = a0[t]; af.u[1] = a1[t];
      aZ0 = mfma16(af.v, wz_reg[0][t], aZ0);
      aZ1 = mfma16(af.v, wz_reg[1][t], aZ1);
    }
    *(f32x4*)&red[w][2][lane * 4] = aZ0;
    *(f32x4*)&red[w][3][lane * 4] = aZ1;
    // ---- per-wave poll of 32 producer-wave flags, then rh loads ----
    if (lane < 32) { while (ld_u32_agent(pollp) < seq) {} }
    asm volatile("" ::: "memory");
    unsigned long long rA[8], rB[8];
    #pragma unroll
    for (int t = 0; t < 8; ++t) {
      const unsigned long long* p =
          (const unsigned long long*)rh2 + grp64 + (long)(w * 8 + t) * 128 + ld64;
      rA[t] = ld_u64_agent(p);
      rB[t] = ld_u64_agent(p + 1);
    }
    __syncthreads();                              // bar2 (z partials visible)
    if (w >= 2) {                                 // z-reduce, tile tz = w-2
      const int tz = w - 2;
      f32x4 accz = *(const f32x4*)&red[0][2 + tz][lane * 4];
      #pragma unroll
      for (int k = 1; k < 4; ++k) { f32x4 p = *(const f32x4*)&red[k][2 + tz][lane * 4]; accz += p; }
      #pragma unroll
      for (int r_ = 0; r_ < 4; ++r_) {
        float xpv = bf2f((unsigned short)(((r_ < 2) ? xz.x : xz.y) >> ((r_ & 1) * 16)));
        zbuf[(q * 4 + r_) * 32 + tz * 16 + n] = sigmoid_fast(accz[r_] + xpv);
      }
    }
    // ============ phase B: c-MFMA ============
    f32x4 cA, cB;
    cA[0]=0.f;cA[1]=0.f;cA[2]=0.f;cA[3]=0.f; cB = cA;
    #pragma unroll
    for (int t = 0; t < 8; ++t) {
      union { unsigned long long u[2]; bf16x8 v; } af;
      af.u[0] = rA[t]; af.u[1] = rB[t];
      cA = mfma16(af.v, wc_reg[0][t], cA);
      cB = mfma16(af.v, wc_reg[1][t], cB);
    }
    *(f32x4*)&red[w][4][lane * 4] = cA;
    *(f32x4*)&red[w][5][lane * 4] = cB;
    __syncthreads();                              // bar3
    // ---- 4-wave produce H ----
    {
      float v0 = 0.f, v1 = 0.f;
      #pragma unroll
      for (int k = 0; k < 4; ++k) {
        v0 += red[k][4 + t0][(w * 16 + n0) * 4 + rr];
        v1 += red[k][4 + t0][(w * 16 + n0 + 1) * 4 + rr];
      }
      float cv0 = tanh_fast(v0 + bf2f(xc0));
      float cv1 = tanh_fast(v1 + bf2f(xc1));
      float z0 = zbuf[prow * 32 + pc],     z1 = zbuf[prow * 32 + pc + 1];
      float h0 = hmaster[prow * 32 + pc],  h1 = hmaster[prow * 32 + pc + 1];
      float hn0 = z0 * h0 + (1.0f - z0) * cv0;
      float hn1 = z1 * h1 + (1.0f - z1) * cv1;
      hmaster[prow * 32 + pc]     = hn0;
      hmaster[prow * 32 + pc + 1] = hn1;
      if (s == S_LEN - 1) {
        Hf[(long)(g * 16 + prow) * HD + bh * 32 + pc]     = hn0;
        Hf[(long)(g * 16 + prow) * HD + bh * 32 + pc + 1] = hn1;
      }
      unsigned int pay = (unsigned)f2bf(hn0) | ((unsigned)f2bf(hn1) << 16);
      st_u32_agent(hb_u32 + (long)(cur ^ 1) * 32768 + my32, pay);
      asm volatile("s_waitcnt vmcnt(0)" ::: "memory");   // own payload at LLC
      if (lane == 0) st_u32_agent(myflag, seq + 1);
    }
    // ============ free-running tail: prefetch + poll + H loads ============
    if (s < S_LEN - 1) {
      const unsigned short* xr_s = xr_p + (long)(s + 1) * xp_step;
      const unsigned short* xc_s = xc_p + (long)(s + 1) * xp_step;
      unsigned short xr0n = xr_s[0], xr1n = xr_s[16];
      unsigned short xc0n = xc_s[0], xc1n = xc_s[16];
      uint2 xzn; xzn.x = 0; xzn.y = 0;
      if (w >= 2) xzn = *(const uint2*)(xz_p + (long)(s + 1) * xp_step);
      if (lane < 32) { while (ld_u32_agent(pollp) < seq + 1) {} }
      asm volatile("" ::: "memory");
      const unsigned long long* hb =
          (const unsigned long long*)Hb2 + (long)(cur ^ 1) * 16384 + grp64;
      #pragma unroll
      for (int t = 0; t < 8; ++t) {
        const unsigned long long* p = hb + (long)(w * 8 + t) * 128 + ld64;
        a0[t] = ld_u64_agent(p);
        a1[t] = ld_u64_agent(p + 1);
      }
      xr0 = xr0n; xr1 = xr1n; xc0 = xc0n; xc1 = xc1n; xz = xzn;
    }
    seq += 2;
    cur ^= 1;
  }
}

// ============================================================================
// logits + softmax: one wave per batch row
// ============================================================================
__global__ void logits_kernel(const float* __restrict__ Hf, const float* __restrict__ Whq,
                              const float* __restrict__ bq, float* __restrict__ out) {
  const int b = blockIdx.x;
  const int lane = threadIdx.x;   // 64
  float acc[O_DIM];
  #pragma unroll
  for (int o = 0; o < O_DIM; ++o) acc[o] = 0.f;
  for (int k = lane; k < HD; k += 64) {
    float h = Hf[(long)b * HD + k];
    #pragma unroll
    for (int o = 0; o < O_DIM; ++o) acc[o] += h * Whq[(long)k * O_DIM + o];
  }
  #pragma unroll
  for (int o = 0; o < O_DIM; ++o) {
    #pragma unroll
    for (int off = 32; off > 0; off >>= 1) acc[o] += __shfl_down(acc[o], off, 64);
  }
  if (lane == 0) {
    float lg[O_DIM], m = -1e30f, sum = 0.f;
    #pragma unroll
    for (int o = 0; o < O_DIM; ++o) { lg[o] = acc[o] + bq[o]; m = fmaxf(m, lg[o]); }
    #pragma unroll
    for (int o = 0; o < O_DIM; ++o) { lg[o] = __expf(lg[o] - m); sum += lg[o]; }
    float inv = 1.0f / sum;
    #pragma unroll
    for (int o = 0; o < O_DIM; ++o) out[(long)b * O_DIM + o] = lg[o] * inv;
  }
}

// ============================================================================
extern "C" void kernel_launch(void* const* d_in, const int* in_sizes, int n_in,
                              void* d_out, int out_size, void* d_ws, size_t ws_size,
                              hipStream_t stream) {
  const int*   tokens = (const int*)d_in[0];
  const float* Emb = (const float*)d_in[1];
  const float* Wxr = (const float*)d_in[2];
  const float* Whr = (const float*)d_in[3];
  const float* br  = (const float*)d_in[4];
  const float* Wxz = (const float*)d_in[5];
  const float* Whz = (const float*)d_in[6];
  const float* bz  = (const float*)d_in[7];
  const float* Wxc = (const float*)d_in[8];
  const float* Whc = (const float*)d_in[9];
  const float* bc  = (const float*)d_in[10];
  const float* Whq = (const float*)d_in[11];
  const float* bq  = (const float*)d_in[12];

  char* ws = (char*)d_ws;
  unsigned short* Hb2    = (unsigned short*)(ws + OFF_HB2);
  unsigned short* rh2    = (unsigned short*)(ws + OFF_RH2);
  float*          Hf     = (float*)(ws + OFF_HF);
  unsigned int*   slots  = (unsigned int*)(ws + OFF_SLOTS);
  unsigned short* Wr_swz = (unsigned short*)(ws + OFF_WR);
  unsigned short* Wz_swz = (unsigned short*)(ws + OFF_WZ);
  unsigned short* Wc_swz = (unsigned short*)(ws + OFF_WC);
  unsigned short* Wx_swz = (unsigned short*)(ws + OFF_WX);
  unsigned short* Xp     = (unsigned short*)(ws + OFF_XP);

  // only the flags need zeroing (H0 in-register; buffers write-before-read)
  hipMemsetAsync(ws + OFF_SLOTS, 0, 131072, stream);

  convert_kernel<<<18432, 256, 0, stream>>>(Whr, Whz, Whc, Wxr, Wxz, Wxc,
                                            Wr_swz, Wz_swz, Wc_swz, Wx_swz);
  embed_kernel<<<dim3(48, S_LEN), 256, 0, stream>>>(tokens, Emb, Wx_swz, br, bz, bc, Xp);
  gru_kernel<<<128, 256, 0, stream>>>(Xp, Wr_swz, Wz_swz, Wc_swz,
                                      Hb2, Hf, rh2, slots);
  logits_kernel<<<B_SZ, 64, 0, stream>>>(Hf, Whq, bq, (float*)d_out);
}